// Round 8
// baseline (111.528 us; speedup 1.0000x reference)
//
#include <hip/hip_runtime.h>
#include <hip/hip_bf16.h>

#define D 256
#define NROWS 8192
#define LXK 4160         // Kx rows per batch: 64 prefix + 4096
#define LXV 4176         // Vt col stride per batch: 64 prefix + 4096 + 16 tail pad
#define VPAD 64

#define QBLK 16          // attn rows per block
#define KKEYS 80         // staged keys per block
#define SSTR 84          // Sb row stride (f32)
#define PSTR 104         // Pb row stride (u16), cols 80..95 zeroed
#define MSTR 264         // Ml row stride (u16)

typedef unsigned int u32;
typedef unsigned short u16;

typedef short bf16x8 __attribute__((ext_vector_type(8)));
typedef float f32x4 __attribute__((ext_vector_type(4)));

__device__ __forceinline__ u16 f2bf(float f) {
    u32 x = __float_as_uint(f);
    x += 0x7fffu + ((x >> 16) & 1u);
    return (u16)(x >> 16);
}
__device__ __forceinline__ u32 pk2(float a, float b) {
    return (u32)f2bf(a) | ((u32)f2bf(b) << 16);
}

// ---------------- Kernel 1: QKV projection (MFMA, in-kernel W transpose) ----------------
__global__ __launch_bounds__(256) void qkv_mfma(
    const float* __restrict__ H,
    const float* __restrict__ Wq, const float* __restrict__ Wk,
    const float* __restrict__ Wv,
    const float* __restrict__ bq, const float* __restrict__ bkb,
    const float* __restrict__ bvb,
    u16* __restrict__ Qb, u16* __restrict__ Kx, u16* __restrict__ Vt)
{
    __shared__ u16 As[64 * 256];
    __shared__ u16 Bs[2][128 * 68];

    const int tid = threadIdx.x;
    const int bx = blockIdx.x;     // 0..5
    const int by = blockIdx.y;     // 0..127
    const int row0 = by * 64;
    const int mat = bx >> 1;       // 0=Q 1=K 2=V
    const int n0 = (bx & 1) * 128;
    const float* __restrict__ W = (mat == 0) ? Wq : (mat == 1) ? Wk : Wv;

    const int kp = tid >> 3, ng = tid & 7;

    float4 wa[4], wb4[4];
    {
        const float* wr0 = W + (size_t)(kp * 2) * 256 + n0 + ng * 16;
        #pragma unroll
        for (int j = 0; j < 4; ++j) {
            wa[j]  = *(const float4*)(wr0 + j * 4);
            wb4[j] = *(const float4*)(wr0 + 256 + j * 4);
        }
    }
    {
        const int r = tid >> 2, cb = (tid & 3) * 64;
        const float* hp = H + (size_t)(row0 + r) * 256 + cb;
        const int swz = (r & 7) << 3;
        #pragma unroll
        for (int i = 0; i < 16; ++i) {
            float4 h4 = *(const float4*)(hp + i * 4);
            uint2 pv; pv.x = pk2(h4.x, h4.y); pv.y = pk2(h4.z, h4.w);
            *(uint2*)(As + ((r * 256 + cb + i * 4) ^ swz)) = pv;
        }
    }
    {
        u32* bd = (u32*)&Bs[0][0];
        #pragma unroll
        for (int j = 0; j < 4; ++j)
            #pragma unroll
            for (int i = 0; i < 4; ++i)
                bd[(ng * 16 + j * 4 + i) * 34 + kp] = pk2(wa[j][i], wb4[j][i]);
    }
    __syncthreads();

    const int lane = tid & 63, w = tid >> 6;
    const int l15 = lane & 15, lhi = lane >> 4;
    const int rowa = w * 16 + l15;
    const int kb = lhi * 8;
    const int swa = (rowa & 7) << 3;

    bf16x8 af[8];
    #pragma unroll
    for (int ks = 0; ks < 8; ++ks)
        af[ks] = *(const bf16x8*)(As + ((rowa * 256 + ks * 32 + kb) ^ swa));

    f32x4 acc[8];
    #pragma unroll
    for (int i = 0; i < 8; ++i) acc[i] = (f32x4){0.f, 0.f, 0.f, 0.f};

    for (int s = 0; s < 4; ++s) {
        if (s < 3) {
            const float* wr0 = W + (size_t)((s + 1) * 64 + kp * 2) * 256 + n0 + ng * 16;
            #pragma unroll
            for (int j = 0; j < 4; ++j) {
                wa[j]  = *(const float4*)(wr0 + j * 4);
                wb4[j] = *(const float4*)(wr0 + 256 + j * 4);
            }
        }
        #pragma unroll
        for (int ks2 = 0; ks2 < 2; ++ks2) {
            const int ks = s * 2 + ks2;
            #pragma unroll
            for (int i = 0; i < 8; ++i) {
                bf16x8 bf = *(const bf16x8*)&Bs[s & 1][(i * 16 + l15) * 68 + ks2 * 32 + kb];
                acc[i] = __builtin_amdgcn_mfma_f32_16x16x32_bf16(af[ks], bf, acc[i], 0, 0, 0);
            }
        }
        if (s < 3) {
            __syncthreads();
            u32* bd = (u32*)&Bs[(s + 1) & 1][0];
            #pragma unroll
            for (int j = 0; j < 4; ++j)
                #pragma unroll
                for (int i = 0; i < 4; ++i)
                    bd[(ng * 16 + j * 4 + i) * 34 + kp] = pk2(wa[j][i], wb4[j][i]);
            __syncthreads();
        }
    }

    const int batch = row0 >> 12, lr0 = row0 & 4095;

    if (mat == 2) {
        u16* Vtmp = As;   // [128][72]
        __syncthreads();
        #pragma unroll
        for (int i = 0; i < 8; ++i) {
            const int dl = i * 16 + l15;
            const float bi = bvb[n0 + dl];
            #pragma unroll
            for (int reg = 0; reg < 4; ++reg) {
                const int key = w * 16 + lhi * 4 + reg;
                Vtmp[dl * 72 + key] = f2bf(acc[i][reg] + bi);
            }
        }
        __syncthreads();
        #pragma unroll
        for (int rep = 0; rep < 2; ++rep) {
            const int dl = rep * 64 + (tid >> 2), q = tid & 3;
            uint4 v0 = *(const uint4*)&Vtmp[dl * 72 + q * 16];
            uint4 v1 = *(const uint4*)&Vtmp[dl * 72 + q * 16 + 8];
            const int gd = n0 + dl;
            u16* dst = Vt + ((size_t)batch * 256 + gd) * LXV + VPAD + lr0 + q * 16;
            *(uint4*)dst = v0;
            *(uint4*)(dst + 8) = v1;
        }
    } else {
        u16* Tq = As;     // [64][136]
        const float* bias = (mat == 0) ? bq : bkb;
        __syncthreads();
        #pragma unroll
        for (int i = 0; i < 8; ++i) {
            const int cl = i * 16 + l15;
            const float bi = bias[n0 + cl];
            #pragma unroll
            for (int reg = 0; reg < 4; ++reg)
                Tq[(w * 16 + lhi * 4 + reg) * 136 + cl] = f2bf(acc[i][reg] + bi);
        }
        __syncthreads();
        {
            const int r = tid >> 2, c32 = (tid & 3) * 32;
            uint4 v0 = *(const uint4*)&Tq[r * 136 + c32];
            uint4 v1 = *(const uint4*)&Tq[r * 136 + c32 + 8];
            uint4 v2 = *(const uint4*)&Tq[r * 136 + c32 + 16];
            uint4 v3 = *(const uint4*)&Tq[r * 136 + c32 + 24];
            u16* dst;
            if (mat == 0) dst = Qb + (size_t)(row0 + r) * 256 + n0 + c32;
            else          dst = Kx + ((size_t)batch * LXK + VPAD + lr0 + r) * 256 + n0 + c32;
            *(uint4*)(dst + 0)  = v0;
            *(uint4*)(dst + 8)  = v1;
            *(uint4*)(dst + 16) = v2;
            *(uint4*)(dst + 24) = v3;
        }
    }

    // virtual prefixes
    if (bx == 2 && (by & 63) == 0) {
        const int batch2 = by >> 6;
        const int rowp = tid >> 2, c64 = (tid & 3) * 64;
        u16* dst = Kx + ((size_t)batch2 * LXK + rowp) * 256 + c64;
        #pragma unroll
        for (int j = 0; j < 8; ++j) {
            float4 a = *(const float4*)&bkb[c64 + j * 8];
            float4 b = *(const float4*)&bkb[c64 + j * 8 + 4];
            uint4 o;
            o.x = pk2(a.x, a.y); o.y = pk2(a.z, a.w);
            o.z = pk2(b.x, b.y); o.w = pk2(b.z, b.w);
            *(uint4*)(dst + j * 8) = o;
        }
    }
    if (bx == 4 && (by & 63) == 0) {
        const int batch2 = by >> 6;
        const u16 val = f2bf(bvb[tid]);
        const u32 vv = (u32)val | ((u32)val << 16);
        uint4 o; o.x = vv; o.y = vv; o.z = vv; o.w = vv;
        u16* dst = Vt + ((size_t)batch2 * 256 + tid) * LXV;
        #pragma unroll
        for (int j = 0; j < 8; ++j) *(uint4*)(dst + j * 8) = o;
    }
}

// ---------------- Kernel 2: fused attention + output projection + residual ----------------
// 16 rows/block, 256 threads, grid 512 (2 blocks/CU, 56.8 KB LDS).
// Phases: stage K -> QK^T -> softmax (+Ws slice0 into dead Ks) -> PV (M->LDS)
// -> 4-slice Wo GEMM -> out = H + M@Wo + bo.
__global__ __launch_bounds__(256) void attn_out(
    const u16* __restrict__ Qb, const u16* __restrict__ Kx,
    const u16* __restrict__ Vt, const float* __restrict__ Wo,
    const float* __restrict__ bo, const float* __restrict__ H,
    float* __restrict__ out)
{
    __shared__ __align__(16) char smem[58112];
    u16*  Ks = (u16*)smem;                 // [80][256] swizzled (dead after QK^T)
    u16*  Ws = (u16*)smem;                 // [256][68] overlays Ks
    float* Sb = (float*)(smem + 40960);    // [16][SSTR]
    u16*  Pb = (u16*)(smem + 46336);       // [16][PSTR]
    u16*  Ml = (u16*)(smem + 49664);       // [16][MSTR]

    const int tid = threadIdx.x;
    const int lane = tid & 63, w = tid >> 6;   // w 0..3
    const int l15 = lane & 15, lhi = lane >> 4;
    const int kp = tid >> 3, ng = tid & 7;
    const int r0 = blockIdx.x * QBLK;
    const int batch = r0 >> 12;
    const int lb0 = r0 & 4095;
    const size_t kbase = (size_t)batch * LXK + lb0;

    // ---- stage K (80 rows, swizzled) ----
    uint4 kreg[10];
    #pragma unroll
    for (int i = 0; i < 10; ++i) {
        const int u = i * 256 + tid;
        const int row = u >> 5, seg = u & 31;
        kreg[i] = *(const uint4*)&Kx[(kbase + row) * 256 + seg * 8];
    }
    #pragma unroll
    for (int i = 0; i < 10; ++i) {
        const int u = i * 256 + tid;
        const int row = u >> 5, seg = u & 31;
        *(uint4*)&Ks[row * 256 + (seg ^ (row & 7)) * 8] = kreg[i];
    }
    __syncthreads();

    // ---- QK^T: 5 keytiles over 4 waves ----
    const float scale = 0.0625f;
    const u16* qp = Qb + (size_t)(r0 + l15) * 256;
    bf16x8 qf[8];
    #pragma unroll
    for (int ks = 0; ks < 8; ++ks) qf[ks] = *(const bf16x8*)(qp + ks * 32 + lhi * 8);
    for (int T = w; T < 5; T += 4) {
        const int key = T * 16 + l15;
        f32x4 acc = (f32x4){0.f, 0.f, 0.f, 0.f};
        #pragma unroll
        for (int ks = 0; ks < 8; ++ks) {
            bf16x8 kf = *(const bf16x8*)&Ks[key * 256 + ((ks * 4 + lhi) ^ (key & 7)) * 8];
            acc = __builtin_amdgcn_mfma_f32_16x16x32_bf16(qf[ks], kf, acc, 0, 0, 0);
        }
        #pragma unroll
        for (int reg = 0; reg < 4; ++reg)
            Sb[(lhi * 4 + reg) * SSTR + T * 16 + l15] = acc[reg] * scale;
    }
    __syncthreads();          // Ks now dead

    // ---- softmax + Ws slice-0 staging ----
    {
        const int ri = w * 4 + lhi;
        const int jb = l15;
        float s5[5];
        float m = -1e30f;
        #pragma unroll
        for (int c = 0; c < 5; ++c) {
            const int j = jb + 16 * c;
            const float x = Sb[ri * SSTR + j];
            const bool v = (j >= ri + 1) && (j <= ri + 64);
            s5[c] = v ? x : -1e30f;
            m = fmaxf(m, s5[c]);
        }
        #pragma unroll
        for (int o = 1; o < 16; o <<= 1) m = fmaxf(m, __shfl_xor(m, o));
        float e5[5], z64 = 0.f, z16 = 0.f, z4 = 0.f;
        #pragma unroll
        for (int c = 0; c < 5; ++c) {
            const int j = jb + 16 * c;
            const float e = __expf(s5[c] - m);
            e5[c] = e;
            z64 += e;
            if (j >= ri + 49) z16 += e;
            if (j >= ri + 61) z4 += e;
        }
        #pragma unroll
        for (int o = 1; o < 16; o <<= 1) {
            z64 += __shfl_xor(z64, o);
            z16 += __shfl_xor(z16, o);
            z4  += __shfl_xor(z4, o);
        }
        const float i64 = 1.f / z64, i16 = 1.f / z16, i4 = 1.f / z4;
        #pragma unroll
        for (int c = 0; c < 5; ++c) {
            const int j = jb + 16 * c;
            float wt = e5[c] * (i64 + (j >= ri + 49 ? i16 : 0.f) + (j >= ri + 61 ? i4 : 0.f)) * (1.f / 3.f);
            Pb[ri * PSTR + j] = f2bf(wt);
        }
        Pb[ri * PSTR + 80 + jb] = 0;
    }
    {   // Ws slice 0: Wo rows 0..63 -> [col][k] packed
        const float* wr0 = Wo + (size_t)(kp * 2) * 256 + ng * 32;
        u32* bd = (u32*)Ws;
        #pragma unroll
        for (int j = 0; j < 8; ++j) {
            float4 a = *(const float4*)(wr0 + j * 4);
            float4 b = *(const float4*)(wr0 + 256 + j * 4);
            bd[(ng * 32 + j * 4 + 0) * 34 + kp] = pk2(a.x, b.x);
            bd[(ng * 32 + j * 4 + 1) * 34 + kp] = pk2(a.y, b.y);
            bd[(ng * 32 + j * 4 + 2) * 34 + kp] = pk2(a.z, b.z);
            bd[(ng * 32 + j * 4 + 3) * 34 + kp] = pk2(a.w, b.w);
        }
    }
    __syncthreads();

    // ---- PV: M[16][256] = P[16][96] @ V^T[96][256] -> Ml ----
    bf16x8 pa[3];
    #pragma unroll
    for (int ks = 0; ks < 3; ++ks)
        pa[ks] = *(const bf16x8*)&Pb[l15 * PSTR + ks * 32 + lhi * 8];
    #pragma unroll
    for (int i = 0; i < 4; ++i) {
        const int dt = w * 4 + i;
        const u16* vrow = Vt + ((size_t)batch * 256 + dt * 16 + l15) * LXV + lb0;
        f32x4 acc = (f32x4){0.f, 0.f, 0.f, 0.f};
        #pragma unroll
        for (int ks = 0; ks < 3; ++ks) {
            bf16x8 vb = *(const bf16x8*)(vrow + ks * 32 + lhi * 8);
            acc = __builtin_amdgcn_mfma_f32_16x16x32_bf16(pa[ks], vb, acc, 0, 0, 0);
        }
        #pragma unroll
        for (int reg = 0; reg < 4; ++reg)
            Ml[(lhi * 4 + reg) * MSTR + dt * 16 + l15] = f2bf(acc[reg]);
    }
    __syncthreads();

    // ---- out-GEMM: out[16][256] = H + M @ WoT + bo; wave w -> cols [64w,64w+64) ----
    bf16x8 afm[8];
    #pragma unroll
    for (int ks = 0; ks < 8; ++ks)
        afm[ks] = *(const bf16x8*)&Ml[l15 * MSTR + ks * 32 + lhi * 8];

    f32x4 oac[4];
    #pragma unroll
    for (int t = 0; t < 4; ++t) oac[t] = (f32x4){0.f, 0.f, 0.f, 0.f};

    for (int s = 0; s < 4; ++s) {
        if (s > 0) {
            __syncthreads();   // prev slice MFMAs done
            const float* wr0 = Wo + (size_t)(s * 64 + kp * 2) * 256 + ng * 32;
            u32* bd = (u32*)Ws;
            #pragma unroll
            for (int j = 0; j < 8; ++j) {
                float4 a = *(const float4*)(wr0 + j * 4);
                float4 b = *(const float4*)(wr0 + 256 + j * 4);
                bd[(ng * 32 + j * 4 + 0) * 34 + kp] = pk2(a.x, b.x);
                bd[(ng * 32 + j * 4 + 1) * 34 + kp] = pk2(a.y, b.y);
                bd[(ng * 32 + j * 4 + 2) * 34 + kp] = pk2(a.z, b.z);
                bd[(ng * 32 + j * 4 + 3) * 34 + kp] = pk2(a.w, b.w);
            }
            __syncthreads();
        }
        #pragma unroll
        for (int ks2 = 0; ks2 < 2; ++ks2) {
            #pragma unroll
            for (int t = 0; t < 4; ++t) {
                bf16x8 bf = *(const bf16x8*)&Ws[((w * 4 + t) * 16 + l15) * 68 + ks2 * 32 + lhi * 8];
                oac[t] = __builtin_amdgcn_mfma_f32_16x16x32_bf16(afm[s * 2 + ks2], bf, oac[t], 0, 0, 0);
            }
        }
    }

    #pragma unroll
    for (int t = 0; t < 4; ++t) {
        const int col = w * 64 + t * 16 + l15;
        const float bi = bo[col];
        #pragma unroll
        for (int reg = 0; reg < 4; ++reg) {
            const int r = r0 + lhi * 4 + reg;
            const size_t off = (size_t)r * 256 + col;
            out[off] = H[off] + oac[t][reg] + bi;
        }
    }
}

extern "C" void kernel_launch(void* const* d_in, const int* in_sizes, int n_in,
                              void* d_out, int out_size, void* d_ws, size_t ws_size,
                              hipStream_t stream) {
    const float* H  = (const float*)d_in[0];
    const float* Wq = (const float*)d_in[1];
    const float* bq = (const float*)d_in[2];
    const float* Wk = (const float*)d_in[3];
    const float* bk = (const float*)d_in[4];
    const float* Wv = (const float*)d_in[5];
    const float* bv = (const float*)d_in[6];
    const float* Wo = (const float*)d_in[7];
    const float* bo = (const float*)d_in[8];
    float* out = (float*)d_out;

    u16* Qb = (u16*)d_ws;                          // 8192*256
    u16* Kx = Qb + (size_t)NROWS * 256;            // 2*LXK*256
    u16* Vt = Kx + (size_t)2 * LXK * 256;          // 2*256*LXV

    qkv_mfma<<<dim3(6, 128), 256, 0, stream>>>(H, Wq, Wk, Wv, bq, bk, bv, Qb, Kx, Vt);
    attn_out<<<512, 256, 0, stream>>>(Qb, Kx, Vt, Wo, bo, H, out);
}

// Round 9
// 62.882 us; speedup vs baseline: 1.7736x; 1.7736x over previous
//
#include <hip/hip_runtime.h>
#include <hip/hip_bf16.h>

#define D 256
#define NROWS 8192
#define LXK 4160         // Kx rows per batch: 64 prefix + 4096
#define LXV 4176         // Vt col stride per batch: 64 prefix + 4096 + 16 tail pad
#define VPAD 64

#define QBLK 16          // attn rows per block
#define KKEYS 80         // staged keys per block
#define SSTR 84          // Sb row stride (f32)
#define PSTR 104         // Pb row stride (u16), cols 80..95 zeroed

typedef unsigned int u32;
typedef unsigned short u16;

typedef short bf16x8 __attribute__((ext_vector_type(8)));
typedef float f32x4 __attribute__((ext_vector_type(4)));

__device__ __forceinline__ u16 f2bf(float f) {
    u32 x = __float_as_uint(f);
    x += 0x7fffu + ((x >> 16) & 1u);
    return (u16)(x >> 16);
}
__device__ __forceinline__ u32 pk2(float a, float b) {
    return (u32)f2bf(a) | ((u32)f2bf(b) << 16);
}

// ---------------- Kernel 1: QKV projection (MFMA, in-kernel W transpose) ----------------
// 32 rows x 128 cols per block over [8192 x 768]; 51.2 KB LDS -> 3 blocks/CU.
// B pack: kp=tid&31 -> bank=(2c+kp)%32 spans 32 banks, 2-way max (free).
__global__ __launch_bounds__(256) void qkv_mfma(
    const float* __restrict__ H,
    const float* __restrict__ Wq, const float* __restrict__ Wk,
    const float* __restrict__ Wv,
    const float* __restrict__ bq, const float* __restrict__ bkb,
    const float* __restrict__ bvb,
    u16* __restrict__ Qb, u16* __restrict__ Kx, u16* __restrict__ Vt)
{
    __shared__ u16 As[32 * 256];
    __shared__ u16 Bs[2][128 * 68];

    const int tid = threadIdx.x;
    const int bx = blockIdx.x;     // 0..5
    const int by = blockIdx.y;     // 0..255
    const int row0 = by * 32;
    const int mat = bx >> 1;       // 0=Q 1=K 2=V
    const int n0 = (bx & 1) * 128;
    const float* __restrict__ W = (mat == 0) ? Wq : (mat == 1) ? Wk : Wv;

    const int kp = tid & 31, ng = tid >> 5;   // k-pair 0..31, col-group 0..7

    float4 wa[4], wb4[4];
    {
        const float* wr0 = W + (size_t)(kp * 2) * 256 + n0 + ng * 16;
        #pragma unroll
        for (int j = 0; j < 4; ++j) {
            wa[j]  = *(const float4*)(wr0 + j * 4);
            wb4[j] = *(const float4*)(wr0 + 256 + j * 4);
        }
    }
    {   // stage A: 32 rows x 256, fp32->bf16, XOR swizzle in 8-u16 units
        const int r = tid >> 3, cb = (tid & 7) * 32;
        const float* hp = H + (size_t)(row0 + r) * 256 + cb;
        const int swz = (r & 7) << 3;
        #pragma unroll
        for (int i = 0; i < 8; ++i) {
            float4 h4 = *(const float4*)(hp + i * 4);
            uint2 pv; pv.x = pk2(h4.x, h4.y); pv.y = pk2(h4.z, h4.w);
            *(uint2*)(As + ((r * 256 + cb + i * 4) ^ swz)) = pv;
        }
    }
    {
        u32* bd = (u32*)&Bs[0][0];
        #pragma unroll
        for (int j = 0; j < 4; ++j)
            #pragma unroll
            for (int i = 0; i < 4; ++i)
                bd[(ng * 16 + j * 4 + i) * 34 + kp] = pk2(wa[j][i], wb4[j][i]);
    }
    __syncthreads();

    const int lane = tid & 63, w = tid >> 6;
    const int l15 = lane & 15, lhi = lane >> 4;
    const int rt = w & 1, cg = (w >> 1) * 4;   // rowtile, coltile base
    const int rowa = rt * 16 + l15;
    const int kb = lhi * 8;
    const int swa = (rowa & 7) << 3;

    bf16x8 af[8];
    #pragma unroll
    for (int ks = 0; ks < 8; ++ks)
        af[ks] = *(const bf16x8*)(As + ((rowa * 256 + ks * 32 + kb) ^ swa));

    f32x4 acc[4];
    #pragma unroll
    for (int i = 0; i < 4; ++i) acc[i] = (f32x4){0.f, 0.f, 0.f, 0.f};

    for (int s = 0; s < 4; ++s) {
        if (s < 3) {
            const float* wr0 = W + (size_t)((s + 1) * 64 + kp * 2) * 256 + n0 + ng * 16;
            #pragma unroll
            for (int j = 0; j < 4; ++j) {
                wa[j]  = *(const float4*)(wr0 + j * 4);
                wb4[j] = *(const float4*)(wr0 + 256 + j * 4);
            }
        }
        #pragma unroll
        for (int ks2 = 0; ks2 < 2; ++ks2) {
            const int ks = s * 2 + ks2;
            #pragma unroll
            for (int i = 0; i < 4; ++i) {
                bf16x8 bf = *(const bf16x8*)&Bs[s & 1][((cg + i) * 16 + l15) * 68 + ks2 * 32 + kb];
                acc[i] = __builtin_amdgcn_mfma_f32_16x16x32_bf16(af[ks], bf, acc[i], 0, 0, 0);
            }
        }
        if (s < 3) {
            __syncthreads();
            u32* bd = (u32*)&Bs[(s + 1) & 1][0];
            #pragma unroll
            for (int j = 0; j < 4; ++j)
                #pragma unroll
                for (int i = 0; i < 4; ++i)
                    bd[(ng * 16 + j * 4 + i) * 34 + kp] = pk2(wa[j][i], wb4[j][i]);
            __syncthreads();
        }
    }

    const int batch = row0 >> 12, lr0 = row0 & 4095;

    if (mat == 2) {
        // V: bounce through LDS (reuse As) for coalesced transposed stores.
        u16* Vtmp = As;   // [128][40]
        __syncthreads();
        #pragma unroll
        for (int i = 0; i < 4; ++i) {
            const int dl = (cg + i) * 16 + l15;          // local dim 0..127
            const float bi = bvb[n0 + dl];
            #pragma unroll
            for (int reg = 0; reg < 4; ++reg) {
                const int key = rt * 16 + lhi * 4 + reg; // local key 0..31
                Vtmp[dl * 40 + key] = f2bf(acc[i][reg] + bi);
            }
        }
        __syncthreads();
        {
            const int dl2 = tid >> 1, half = tid & 1;
            uint4 v0 = *(const uint4*)&Vtmp[dl2 * 40 + half * 16];
            uint4 v1 = *(const uint4*)&Vtmp[dl2 * 40 + half * 16 + 8];
            u16* dst = Vt + ((size_t)batch * 256 + n0 + dl2) * LXV + VPAD + lr0 + half * 16;
            *(uint4*)dst = v0;
            *(uint4*)(dst + 8) = v1;
        }
    } else {
        // Q/K: bounce through LDS (reuse As) for coalesced row stores.
        u16* Tq = As;     // [32][136]
        const float* bias = (mat == 0) ? bq : bkb;
        __syncthreads();
        #pragma unroll
        for (int i = 0; i < 4; ++i) {
            const int cl = (cg + i) * 16 + l15;
            const float bi = bias[n0 + cl];
            #pragma unroll
            for (int reg = 0; reg < 4; ++reg)
                Tq[(rt * 16 + lhi * 4 + reg) * 136 + cl] = f2bf(acc[i][reg] + bi);
        }
        __syncthreads();
        {
            const int r2 = tid >> 3, c16 = (tid & 7) * 16;
            uint4 v0 = *(const uint4*)&Tq[r2 * 136 + c16];
            uint4 v1 = *(const uint4*)&Tq[r2 * 136 + c16 + 8];
            u16* dst;
            if (mat == 0) dst = Qb + (size_t)(row0 + r2) * 256 + n0 + c16;
            else          dst = Kx + ((size_t)batch * LXK + VPAD + lr0 + r2) * 256 + n0 + c16;
            *(uint4*)(dst + 0) = v0;
            *(uint4*)(dst + 8) = v1;
        }
    }

    // ---- virtual-prefix writes (designated blocks) ----
    if (bx == 2 && (by & 127) == 0) {          // Kx prefix rows = bk
        const int batch2 = by >> 7;
        const int rowp = tid >> 2, c64 = (tid & 3) * 64;
        u16* dst = Kx + ((size_t)batch2 * LXK + rowp) * 256 + c64;
        #pragma unroll
        for (int j = 0; j < 8; ++j) {
            float4 a = *(const float4*)&bkb[c64 + j * 8];
            float4 b = *(const float4*)&bkb[c64 + j * 8 + 4];
            uint4 o;
            o.x = pk2(a.x, a.y); o.y = pk2(a.z, a.w);
            o.z = pk2(b.x, b.y); o.w = pk2(b.z, b.w);
            *(uint4*)(dst + j * 8) = o;
        }
    }
    if (bx == 4 && (by & 127) == 0) {          // Vt prefix cols = bv
        const int batch2 = by >> 7;
        const u16 val = f2bf(bvb[tid]);
        const u32 vv = (u32)val | ((u32)val << 16);
        uint4 o; o.x = vv; o.y = vv; o.z = vv; o.w = vv;
        u16* dst = Vt + ((size_t)batch2 * 256 + tid) * LXV;
        #pragma unroll
        for (int j = 0; j < 8; ++j) *(uint4*)(dst + j * 8) = o;
    }
}

// ---------------- Kernel 2: fused 3-window attention (MFMA) ----------------
// (verbatim R7: 16 rows/block, 256 threads, grid 512; K swizzled in LDS, V^T from global)
__global__ __launch_bounds__(256) void attn_mfma(
    const u16* __restrict__ Qb, const u16* __restrict__ Kx,
    const u16* __restrict__ Vt, u16* __restrict__ Mb)
{
    __shared__ u16 Ks[KKEYS * 256];       // XOR-swizzled [key][feat]
    __shared__ float Sb[QBLK * SSTR];
    __shared__ u16 Pb[QBLK * PSTR];

    const int tid = threadIdx.x;
    const int lane = tid & 63, w = tid >> 6;   // w 0..3
    const int l15 = lane & 15, lhi = lane >> 4;
    const int r0 = blockIdx.x * QBLK;
    const int batch = r0 >> 12;
    const int lb0 = r0 & 4095;
    const size_t kbase = (size_t)batch * LXK + lb0;

    uint4 kreg[10];
    #pragma unroll
    for (int i = 0; i < 10; ++i) {
        const int u = i * 256 + tid;
        const int row = u >> 5, seg = u & 31;
        kreg[i] = *(const uint4*)&Kx[(kbase + row) * 256 + seg * 8];
    }
    #pragma unroll
    for (int i = 0; i < 10; ++i) {
        const int u = i * 256 + tid;
        const int row = u >> 5, seg = u & 31;
        *(uint4*)&Ks[row * 256 + (seg ^ (row & 7)) * 8] = kreg[i];
    }
    __syncthreads();

    const float scale = 0.0625f;
    const u16* qp = Qb + (size_t)(r0 + l15) * 256;
    bf16x8 qf[8];
    #pragma unroll
    for (int ks = 0; ks < 8; ++ks) qf[ks] = *(const bf16x8*)(qp + ks * 32 + lhi * 8);
    for (int T = w; T < 5; T += 4) {
        const int key = T * 16 + l15;
        f32x4 acc = (f32x4){0.f, 0.f, 0.f, 0.f};
        #pragma unroll
        for (int ks = 0; ks < 8; ++ks) {
            bf16x8 kf = *(const bf16x8*)&Ks[key * 256 + ((ks * 4 + lhi) ^ (key & 7)) * 8];
            acc = __builtin_amdgcn_mfma_f32_16x16x32_bf16(qf[ks], kf, acc, 0, 0, 0);
        }
        #pragma unroll
        for (int reg = 0; reg < 4; ++reg)
            Sb[(lhi * 4 + reg) * SSTR + T * 16 + l15] = acc[reg] * scale;
    }
    __syncthreads();

    {
        const int ri = w * 4 + lhi;
        const int jb = l15;
        float s5[5];
        float m = -1e30f;
        #pragma unroll
        for (int c = 0; c < 5; ++c) {
            const int j = jb + 16 * c;
            const float x = Sb[ri * SSTR + j];
            const bool v = (j >= ri + 1) && (j <= ri + 64);
            s5[c] = v ? x : -1e30f;
            m = fmaxf(m, s5[c]);
        }
        #pragma unroll
        for (int o = 1; o < 16; o <<= 1) m = fmaxf(m, __shfl_xor(m, o));
        float e5[5], z64 = 0.f, z16 = 0.f, z4 = 0.f;
        #pragma unroll
        for (int c = 0; c < 5; ++c) {
            const int j = jb + 16 * c;
            const float e = __expf(s5[c] - m);
            e5[c] = e;
            z64 += e;
            if (j >= ri + 49) z16 += e;
            if (j >= ri + 61) z4 += e;
        }
        #pragma unroll
        for (int o = 1; o < 16; o <<= 1) {
            z64 += __shfl_xor(z64, o);
            z16 += __shfl_xor(z16, o);
            z4  += __shfl_xor(z4, o);
        }
        const float i64 = 1.f / z64, i16 = 1.f / z16, i4 = 1.f / z4;
        #pragma unroll
        for (int c = 0; c < 5; ++c) {
            const int j = jb + 16 * c;
            float wt = e5[c] * (i64 + (j >= ri + 49 ? i16 : 0.f) + (j >= ri + 61 ? i4 : 0.f)) * (1.f / 3.f);
            Pb[ri * PSTR + j] = f2bf(wt);
        }
        Pb[ri * PSTR + 80 + jb] = 0;
    }
    __syncthreads();

    bf16x8 pa[3];
    #pragma unroll
    for (int ks = 0; ks < 3; ++ks)
        pa[ks] = *(const bf16x8*)&Pb[l15 * PSTR + ks * 32 + lhi * 8];
    #pragma unroll
    for (int i = 0; i < 4; ++i) {
        const int dt = w * 4 + i;
        const u16* vrow = Vt + ((size_t)batch * 256 + dt * 16 + l15) * LXV + lb0;
        f32x4 acc = (f32x4){0.f, 0.f, 0.f, 0.f};
        #pragma unroll
        for (int ks = 0; ks < 3; ++ks) {
            bf16x8 vb = *(const bf16x8*)(vrow + ks * 32 + lhi * 8);
            acc = __builtin_amdgcn_mfma_f32_16x16x32_bf16(pa[ks], vb, acc, 0, 0, 0);
        }
        #pragma unroll
        for (int reg = 0; reg < 4; ++reg)
            Mb[(size_t)(r0 + lhi * 4 + reg) * 256 + dt * 16 + l15] = f2bf(acc[reg]);
    }
}

// ---------------- Kernel 3: output projection + residual (32-row tiles) ----------------
__global__ __launch_bounds__(256) void out_mfma(
    const u16* __restrict__ Mb, const float* __restrict__ Wo,
    const float* __restrict__ bo, const float* __restrict__ H,
    float* __restrict__ out)
{
    __shared__ u16 As[32 * 256];
    __shared__ u16 Bs[2][128 * 68];

    const int tid = threadIdx.x;
    const int bx = blockIdx.x;     // 0..1
    const int by = blockIdx.y;     // 0..255
    const int row0 = by * 32;
    const int n0 = bx * 128;
    const int kp = tid & 31, ng = tid >> 5;

    float4 wa[4], wb4[4];
    {
        const float* wr0 = Wo + (size_t)(kp * 2) * 256 + n0 + ng * 16;
        #pragma unroll
        for (int j = 0; j < 4; ++j) {
            wa[j]  = *(const float4*)(wr0 + j * 4);
            wb4[j] = *(const float4*)(wr0 + 256 + j * 4);
        }
    }
    {
        const int r = tid >> 3, cb = (tid & 7) * 32;
        const u16* mp = Mb + (size_t)(row0 + r) * 256 + cb;
        const int swz = (r & 7) << 3;
        #pragma unroll
        for (int i = 0; i < 4; ++i) {
            uint4 v = *(const uint4*)(mp + i * 8);
            *(uint4*)(As + ((r * 256 + cb + i * 8) ^ swz)) = v;
        }
    }
    {
        u32* bd = (u32*)&Bs[0][0];
        #pragma unroll
        for (int j = 0; j < 4; ++j)
            #pragma unroll
            for (int i = 0; i < 4; ++i)
                bd[(ng * 16 + j * 4 + i) * 34 + kp] = pk2(wa[j][i], wb4[j][i]);
    }
    __syncthreads();

    const int lane = tid & 63, w = tid >> 6;
    const int l15 = lane & 15, lhi = lane >> 4;
    const int rt = w & 1, cg = (w >> 1) * 4;
    const int rowa = rt * 16 + l15;
    const int kb = lhi * 8;
    const int swa = (rowa & 7) << 3;

    bf16x8 af[8];
    #pragma unroll
    for (int ks = 0; ks < 8; ++ks)
        af[ks] = *(const bf16x8*)(As + ((rowa * 256 + ks * 32 + kb) ^ swa));

    f32x4 acc[4];
    #pragma unroll
    for (int i = 0; i < 4; ++i) acc[i] = (f32x4){0.f, 0.f, 0.f, 0.f};

    for (int s = 0; s < 4; ++s) {
        if (s < 3) {
            const float* wr0 = Wo + (size_t)((s + 1) * 64 + kp * 2) * 256 + n0 + ng * 16;
            #pragma unroll
            for (int j = 0; j < 4; ++j) {
                wa[j]  = *(const float4*)(wr0 + j * 4);
                wb4[j] = *(const float4*)(wr0 + 256 + j * 4);
            }
        }
        #pragma unroll
        for (int ks2 = 0; ks2 < 2; ++ks2) {
            const int ks = s * 2 + ks2;
            #pragma unroll
            for (int i = 0; i < 4; ++i) {
                bf16x8 bf = *(const bf16x8*)&Bs[s & 1][((cg + i) * 16 + l15) * 68 + ks2 * 32 + kb];
                acc[i] = __builtin_amdgcn_mfma_f32_16x16x32_bf16(af[ks], bf, acc[i], 0, 0, 0);
            }
        }
        if (s < 3) {
            __syncthreads();
            u32* bd = (u32*)&Bs[(s + 1) & 1][0];
            #pragma unroll
            for (int j = 0; j < 4; ++j)
                #pragma unroll
                for (int i = 0; i < 4; ++i)
                    bd[(ng * 16 + j * 4 + i) * 34 + kp] = pk2(wa[j][i], wb4[j][i]);
            __syncthreads();
        }
    }

    #pragma unroll
    for (int i = 0; i < 4; ++i) {
        const int col = n0 + (cg + i) * 16 + l15;
        const float bi = bo[col];
        #pragma unroll
        for (int reg = 0; reg < 4; ++reg) {
            const int r = row0 + rt * 16 + lhi * 4 + reg;
            const size_t off = (size_t)r * 256 + col;
            out[off] = H[off] + acc[i][reg] + bi;
        }
    }
}

extern "C" void kernel_launch(void* const* d_in, const int* in_sizes, int n_in,
                              void* d_out, int out_size, void* d_ws, size_t ws_size,
                              hipStream_t stream) {
    const float* H  = (const float*)d_in[0];
    const float* Wq = (const float*)d_in[1];
    const float* bq = (const float*)d_in[2];
    const float* Wk = (const float*)d_in[3];
    const float* bk = (const float*)d_in[4];
    const float* Wv = (const float*)d_in[5];
    const float* bv = (const float*)d_in[6];
    const float* Wo = (const float*)d_in[7];
    const float* bo = (const float*)d_in[8];
    float* out = (float*)d_out;

    u16* Qb = (u16*)d_ws;                          // 8192*256
    u16* Kx = Qb + (size_t)NROWS * 256;            // 2*LXK*256
    u16* Vt = Kx + (size_t)2 * LXK * 256;          // 2*256*LXV
    u16* Mb = Vt + (size_t)2 * 256 * LXV;          // 8192*256

    qkv_mfma<<<dim3(6, 256), 256, 0, stream>>>(H, Wq, Wk, Wv, bq, bk, bv, Qb, Kx, Vt);
    attn_mfma<<<512, 256, 0, stream>>>(Qb, Kx, Vt, Mb);
    out_mfma<<<dim3(2, 256), 256, 0, stream>>>(Mb, Wo, bo, H, out);
}

// Round 10
// 51.239 us; speedup vs baseline: 2.1766x; 1.2272x over previous
//
#include <hip/hip_runtime.h>
#include <hip/hip_bf16.h>

#define D 256
#define NROWS 8192
#define LXK 4160         // Kx rows per batch: 64 prefix + 4096
#define LXV 4176         // Vt col stride per batch: 64 prefix + 4096 + 16 tail pad
#define VPAD 64

#define QBLK 16          // attn rows per block
#define KKEYS 80         // staged keys per block
#define SSTR 84          // Sb row stride (f32)
#define PSTR 104         // Pb row stride (u16), cols 80..95 zeroed
#define MSTR 264         // Ml row stride (u16): 132 dw == 4 mod 32, b128 reads at conflict floor
#define BSTR 264         // Bs row stride (u16): [n][k] all-256k resident

typedef unsigned int u32;
typedef unsigned short u16;

typedef short bf16x8 __attribute__((ext_vector_type(8)));
typedef float f32x4 __attribute__((ext_vector_type(4)));

__device__ __forceinline__ u16 f2bf(float f) {
    u32 x = __float_as_uint(f);
    x += 0x7fffu + ((x >> 16) & 1u);
    return (u16)(x >> 16);
}
__device__ __forceinline__ u32 pk2(float a, float b) {
    return (u32)f2bf(a) | ((u32)f2bf(b) << 16);
}

// ---------------- Kernel 1: QKV projection (W staged ONCE per block) ----------------
// grid (12, 32): bx -> 64-col slab (mat = bx>>2, cols (bx&3)*64), by -> 256-row group
// (4 x 64-row tiles). Also: bx==0,by<16 produce WoT tiles; bx==4/8,(by&15)==0 prefixes.
__global__ __launch_bounds__(256) void qkv_mfma(
    const float* __restrict__ H,
    const float* __restrict__ Wq, const float* __restrict__ Wk,
    const float* __restrict__ Wv, const float* __restrict__ Wo,
    const float* __restrict__ bq, const float* __restrict__ bkb,
    const float* __restrict__ bvb,
    u16* __restrict__ Qb, u16* __restrict__ Kx, u16* __restrict__ Vt,
    u16* __restrict__ WoT)
{
    __shared__ u16 As[64 * 256];        // 32768 B (A tile, XOR-swizzled)
    __shared__ u16 Bs[64 * BSTR];       // 33792 B (W^T slab, [n][k] packed)
    __shared__ u16 Eb[64 * 72];         // 9216 B  (epilogue bounce)

    const int tid = threadIdx.x;
    const int bx = blockIdx.x;          // 0..11
    const int by = blockIdx.y;          // 0..31
    const int mat = bx >> 2;            // 0=Q 1=K 2=V
    const int n0 = (bx & 3) * 64;       // col offset within matrix
    const int row0 = by * 256;
    const int batch = by >> 4;
    const int lrow0 = row0 & 4095;
    const float* __restrict__ W = (mat == 0) ? Wq : (mat == 1) ? Wk : Wv;
    const float* __restrict__ bias = (mat == 0) ? bq : (mat == 1) ? bkb : bvb;

    const int lane = tid & 63, w = tid >> 6;
    const int l15 = lane & 15, lhi = lane >> 4;
    const int rt2 = (w & 1) * 2, ct2 = (w >> 1) * 2;

    // ---- stage B once: Bs[n][k] = bf16(W[k][n0+n]), k-pair packed ----
    {
        const int kp = tid & 31, ng = tid >> 5;      // k-pair, col-group(8)
        u32* bd = (u32*)Bs;
        #pragma unroll
        for (int s = 0; s < 4; ++s) {
            const float* wr = W + (size_t)(s * 64 + 2 * kp) * 256 + n0 + ng * 8;
            float4 a0 = *(const float4*)(wr);
            float4 a1 = *(const float4*)(wr + 4);
            float4 b0 = *(const float4*)(wr + 256);
            float4 b1 = *(const float4*)(wr + 260);
            bd[(ng * 8 + 0) * 132 + s * 32 + kp] = pk2(a0.x, b0.x);
            bd[(ng * 8 + 1) * 132 + s * 32 + kp] = pk2(a0.y, b0.y);
            bd[(ng * 8 + 2) * 132 + s * 32 + kp] = pk2(a0.z, b0.z);
            bd[(ng * 8 + 3) * 132 + s * 32 + kp] = pk2(a0.w, b0.w);
            bd[(ng * 8 + 4) * 132 + s * 32 + kp] = pk2(a1.x, b1.x);
            bd[(ng * 8 + 5) * 132 + s * 32 + kp] = pk2(a1.y, b1.y);
            bd[(ng * 8 + 6) * 132 + s * 32 + kp] = pk2(a1.z, b1.z);
            bd[(ng * 8 + 7) * 132 + s * 32 + kp] = pk2(a1.w, b1.w);
        }
    }
    // ---- stage A tile 0 ----
    {
        const int r = tid >> 2, cb = (tid & 3) * 64;
        const float* hp = H + (size_t)(row0 + r) * 256 + cb;
        const int swz = (r & 7) << 3;
        #pragma unroll
        for (int i = 0; i < 16; ++i) {
            float4 h4 = *(const float4*)(hp + i * 4);
            uint2 pv; pv.x = pk2(h4.x, h4.y); pv.y = pk2(h4.z, h4.w);
            *(uint2*)(As + ((r * 256 + cb + i * 4) ^ swz)) = pv;
        }
    }
    __syncthreads();

    for (int t = 0; t < 4; ++t) {
        // ---- MFMA(t): wave -> 2x2 16-tiles ----
        f32x4 acc[2][2];
        #pragma unroll
        for (int rr = 0; rr < 2; ++rr)
            #pragma unroll
            for (int cc = 0; cc < 2; ++cc)
                acc[rr][cc] = (f32x4){0.f, 0.f, 0.f, 0.f};
        #pragma unroll
        for (int rr = 0; rr < 2; ++rr) {
            const int rowa = (rt2 + rr) * 16 + l15;
            const int swa = (rowa & 7) << 3;
            bf16x8 af[8];
            #pragma unroll
            for (int ks = 0; ks < 8; ++ks)
                af[ks] = *(const bf16x8*)(As + ((rowa * 256 + ks * 32 + lhi * 8) ^ swa));
            #pragma unroll
            for (int ks = 0; ks < 8; ++ks)
                #pragma unroll
                for (int cc = 0; cc < 2; ++cc) {
                    bf16x8 bf = *(const bf16x8*)&Bs[((ct2 + cc) * 16 + l15) * BSTR + ks * 32 + lhi * 8];
                    acc[rr][cc] = __builtin_amdgcn_mfma_f32_16x16x32_bf16(af[ks], bf, acc[rr][cc], 0, 0, 0);
                }
        }
        __syncthreads();

        // ---- epilogue writes (Eb) + next A stage ----
        if (mat == 2) {
            #pragma unroll
            for (int cc = 0; cc < 2; ++cc) {
                const int dl = (ct2 + cc) * 16 + l15;          // local dim
                const float bi = bvb[n0 + dl];
                #pragma unroll
                for (int rr = 0; rr < 2; ++rr)
                    #pragma unroll
                    for (int reg = 0; reg < 4; ++reg)
                        Eb[dl * 72 + (rt2 + rr) * 16 + lhi * 4 + reg] = f2bf(acc[rr][cc][reg] + bi);
            }
        } else {
            #pragma unroll
            for (int cc = 0; cc < 2; ++cc) {
                const int cl = (ct2 + cc) * 16 + l15;
                const float bi = bias[n0 + cl];
                #pragma unroll
                for (int rr = 0; rr < 2; ++rr)
                    #pragma unroll
                    for (int reg = 0; reg < 4; ++reg)
                        Eb[((rt2 + rr) * 16 + lhi * 4 + reg) * 72 + cl] = f2bf(acc[rr][cc][reg] + bi);
            }
        }
        if (t < 3) {
            const int r = tid >> 2, cb = (tid & 3) * 64;
            const float* hp = H + (size_t)(row0 + (t + 1) * 64 + r) * 256 + cb;
            const int swz = (r & 7) << 3;
            #pragma unroll
            for (int i = 0; i < 16; ++i) {
                float4 h4 = *(const float4*)(hp + i * 4);
                uint2 pv; pv.x = pk2(h4.x, h4.y); pv.y = pk2(h4.z, h4.w);
                *(uint2*)(As + ((r * 256 + cb + i * 4) ^ swz)) = pv;
            }
        }
        __syncthreads();

        // ---- coalesced stores from Eb ----
        if (mat == 2) {
            const int d2 = tid >> 2, q = tid & 3;
            uint4 v0 = *(const uint4*)&Eb[d2 * 72 + q * 16];
            uint4 v1 = *(const uint4*)&Eb[d2 * 72 + q * 16 + 8];
            u16* dst = Vt + ((size_t)batch * 256 + n0 + d2) * LXV + VPAD + lrow0 + t * 64 + q * 16;
            *(uint4*)dst = v0;
            *(uint4*)(dst + 8) = v1;
        } else {
            const int r2 = tid >> 2, c16 = (tid & 3) * 16;
            uint4 v0 = *(const uint4*)&Eb[r2 * 72 + c16];
            uint4 v1 = *(const uint4*)&Eb[r2 * 72 + c16 + 8];
            u16* dst;
            if (mat == 0) dst = Qb + (size_t)(row0 + t * 64 + r2) * 256 + n0 + c16;
            else          dst = Kx + ((size_t)batch * LXK + VPAD + lrow0 + t * 64 + r2) * 256 + n0 + c16;
            *(uint4*)(dst + 0) = v0;
            *(uint4*)(dst + 8) = v1;
        }
    }

    // ---- WoT production: 16 blocks, one 64x64 tile each ----
    if (bx == 0 && by < 16) {
        float* Tf = (float*)As;     // [64][68] f32 = 17.4 KB (As free)
        const int tr = by >> 2, tc = by & 3;
        __syncthreads();
        {
            const int r = tid >> 2, c0 = (tid & 3) * 16;
            const float* src = Wo + (size_t)(tr * 64 + r) * 256 + tc * 64 + c0;
            #pragma unroll
            for (int i = 0; i < 4; ++i) {
                float4 v = *(const float4*)(src + i * 4);
                Tf[r * 68 + c0 + i * 4 + 0] = v.x;
                Tf[r * 68 + c0 + i * 4 + 1] = v.y;
                Tf[r * 68 + c0 + i * 4 + 2] = v.z;
                Tf[r * 68 + c0 + i * 4 + 3] = v.w;
            }
        }
        __syncthreads();
        {
            const int n = tid >> 2, k0 = (tid & 3) * 16;
            u32 pw[8];
            #pragma unroll
            for (int i = 0; i < 8; ++i)
                pw[i] = pk2(Tf[(k0 + 2 * i) * 68 + n], Tf[(k0 + 2 * i + 1) * 68 + n]);
            uint4* dst = (uint4*)&WoT[(size_t)(tc * 64 + n) * 256 + tr * 64 + k0];
            dst[0] = *(uint4*)&pw[0];
            dst[1] = *(uint4*)&pw[4];
        }
    }
    // ---- virtual prefixes ----
    if (bx == 4 && (by & 15) == 0) {          // Kx prefix rows = bk
        const int batch2 = by >> 4;
        const int rowp = tid >> 2, c64 = (tid & 3) * 64;
        u16* dst = Kx + ((size_t)batch2 * LXK + rowp) * 256 + c64;
        #pragma unroll
        for (int j = 0; j < 8; ++j) {
            float4 a = *(const float4*)&bkb[c64 + j * 8];
            float4 b = *(const float4*)&bkb[c64 + j * 8 + 4];
            uint4 o;
            o.x = pk2(a.x, a.y); o.y = pk2(a.z, a.w);
            o.z = pk2(b.x, b.y); o.w = pk2(b.z, b.w);
            *(uint4*)(dst + j * 8) = o;
        }
    }
    if (bx == 8 && (by & 15) == 0) {          // Vt prefix cols = bv
        const int batch2 = by >> 4;
        const u16 val = f2bf(bvb[tid]);
        const u32 vv = (u32)val | ((u32)val << 16);
        uint4 o; o.x = vv; o.y = vv; o.z = vv; o.w = vv;
        u16* dst = Vt + ((size_t)batch2 * 256 + tid) * LXV;
        #pragma unroll
        for (int j = 0; j < 8; ++j) *(uint4*)(dst + j * 8) = o;
    }
}

// ---------------- Kernel 2: fused attention + out-projection + residual ----------------
// R7 attn structure (16 rows/block, grid 512, 49.7 KB LDS -> 3 blocks/CU);
// PV -> Ml (overlays dead Ks); out-GEMM b-frags straight from global WoT.
__global__ __launch_bounds__(256) void attn_out(
    const u16* __restrict__ Qb, const u16* __restrict__ Kx,
    const u16* __restrict__ Vt, const u16* __restrict__ WoT,
    const float* __restrict__ bo, const float* __restrict__ H,
    float* __restrict__ out)
{
    __shared__ __align__(16) char smem[49664];
    u16*  Ks = (u16*)smem;                 // [80][256] swizzled (dead after QK^T)
    u16*  Ml = (u16*)smem;                 // [16][MSTR] overlays Ks
    float* Sb = (float*)(smem + 40960);    // [16][SSTR]
    u16*  Pb = (u16*)(smem + 46336);       // [16][PSTR]

    const int tid = threadIdx.x;
    const int lane = tid & 63, w = tid >> 6;   // w 0..3
    const int l15 = lane & 15, lhi = lane >> 4;
    const int r0 = blockIdx.x * QBLK;
    const int batch = r0 >> 12;
    const int lb0 = r0 & 4095;
    const size_t kbase = (size_t)batch * LXK + lb0;

    // ---- stage K (80 rows, swizzled) ----
    uint4 kreg[10];
    #pragma unroll
    for (int i = 0; i < 10; ++i) {
        const int u = i * 256 + tid;
        const int row = u >> 5, seg = u & 31;
        kreg[i] = *(const uint4*)&Kx[(kbase + row) * 256 + seg * 8];
    }
    #pragma unroll
    for (int i = 0; i < 10; ++i) {
        const int u = i * 256 + tid;
        const int row = u >> 5, seg = u & 31;
        *(uint4*)&Ks[row * 256 + (seg ^ (row & 7)) * 8] = kreg[i];
    }
    __syncthreads();

    // ---- QK^T ----
    const float scale = 0.0625f;
    const u16* qp = Qb + (size_t)(r0 + l15) * 256;
    bf16x8 qf[8];
    #pragma unroll
    for (int ks = 0; ks < 8; ++ks) qf[ks] = *(const bf16x8*)(qp + ks * 32 + lhi * 8);
    for (int T = w; T < 5; T += 4) {
        const int key = T * 16 + l15;
        f32x4 acc = (f32x4){0.f, 0.f, 0.f, 0.f};
        #pragma unroll
        for (int ks = 0; ks < 8; ++ks) {
            bf16x8 kf = *(const bf16x8*)&Ks[key * 256 + ((ks * 4 + lhi) ^ (key & 7)) * 8];
            acc = __builtin_amdgcn_mfma_f32_16x16x32_bf16(qf[ks], kf, acc, 0, 0, 0);
        }
        #pragma unroll
        for (int reg = 0; reg < 4; ++reg)
            Sb[(lhi * 4 + reg) * SSTR + T * 16 + l15] = acc[reg] * scale;
    }
    __syncthreads();

    // ---- nested softmax ----
    {
        const int ri = w * 4 + lhi;
        const int jb = l15;
        float s5[5];
        float m = -1e30f;
        #pragma unroll
        for (int c = 0; c < 5; ++c) {
            const int j = jb + 16 * c;
            const float x = Sb[ri * SSTR + j];
            const bool v = (j >= ri + 1) && (j <= ri + 64);
            s5[c] = v ? x : -1e30f;
            m = fmaxf(m, s5[c]);
        }
        #pragma unroll
        for (int o = 1; o < 16; o <<= 1) m = fmaxf(m, __shfl_xor(m, o));
        float e5[5], z64 = 0.f, z16 = 0.f, z4 = 0.f;
        #pragma unroll
        for (int c = 0; c < 5; ++c) {
            const int j = jb + 16 * c;
            const float e = __expf(s5[c] - m);
            e5[c] = e;
            z64 += e;
            if (j >= ri + 49) z16 += e;
            if (j >= ri + 61) z4 += e;
        }
        #pragma unroll
        for (int o = 1; o < 16; o <<= 1) {
            z64 += __shfl_xor(z64, o);
            z16 += __shfl_xor(z16, o);
            z4  += __shfl_xor(z4, o);
        }
        const float i64 = 1.f / z64, i16 = 1.f / z16, i4 = 1.f / z4;
        #pragma unroll
        for (int c = 0; c < 5; ++c) {
            const int j = jb + 16 * c;
            float wt = e5[c] * (i64 + (j >= ri + 49 ? i16 : 0.f) + (j >= ri + 61 ? i4 : 0.f)) * (1.f / 3.f);
            Pb[ri * PSTR + j] = f2bf(wt);
        }
        Pb[ri * PSTR + 80 + jb] = 0;
    }
    __syncthreads();

    // ---- PV: M[16][256] -> Ml (LDS); V fragments from global ----
    bf16x8 pa[3];
    #pragma unroll
    for (int ks = 0; ks < 3; ++ks)
        pa[ks] = *(const bf16x8*)&Pb[l15 * PSTR + ks * 32 + lhi * 8];
    #pragma unroll
    for (int i = 0; i < 4; ++i) {
        const int dt = w * 4 + i;
        const u16* vrow = Vt + ((size_t)batch * 256 + dt * 16 + l15) * LXV + lb0;
        f32x4 acc = (f32x4){0.f, 0.f, 0.f, 0.f};
        #pragma unroll
        for (int ks = 0; ks < 3; ++ks) {
            bf16x8 vb = *(const bf16x8*)(vrow + ks * 32 + lhi * 8);
            acc = __builtin_amdgcn_mfma_f32_16x16x32_bf16(pa[ks], vb, acc, 0, 0, 0);
        }
        #pragma unroll
        for (int reg = 0; reg < 4; ++reg)
            Ml[(lhi * 4 + reg) * MSTR + dt * 16 + l15] = f2bf(acc[reg]);
    }
    __syncthreads();

    // ---- out-GEMM: out[16][256] = H + M @ Wo + bo; wave w -> cols [64w, 64w+64) ----
    bf16x8 afm[8];
    #pragma unroll
    for (int ks = 0; ks < 8; ++ks)
        afm[ks] = *(const bf16x8*)&Ml[l15 * MSTR + ks * 32 + lhi * 8];

    #pragma unroll
    for (int ct = 0; ct < 4; ++ct) {
        const int col = w * 64 + ct * 16 + l15;
        const u16* wrow = WoT + (size_t)col * 256;
        f32x4 oac = (f32x4){0.f, 0.f, 0.f, 0.f};
        #pragma unroll
        for (int ks = 0; ks < 8; ++ks) {
            bf16x8 bf = *(const bf16x8*)(wrow + ks * 32 + lhi * 8);
            oac = __builtin_amdgcn_mfma_f32_16x16x32_bf16(afm[ks], bf, oac, 0, 0, 0);
        }
        const float bi = bo[col];
        #pragma unroll
        for (int reg = 0; reg < 4; ++reg) {
            const int r = r0 + lhi * 4 + reg;
            const size_t off = (size_t)r * 256 + col;
            out[off] = H[off] + oac[reg] + bi;
        }
    }
}

extern "C" void kernel_launch(void* const* d_in, const int* in_sizes, int n_in,
                              void* d_out, int out_size, void* d_ws, size_t ws_size,
                              hipStream_t stream) {
    const float* H  = (const float*)d_in[0];
    const float* Wq = (const float*)d_in[1];
    const float* bq = (const float*)d_in[2];
    const float* Wk = (const float*)d_in[3];
    const float* bk = (const float*)d_in[4];
    const float* Wv = (const float*)d_in[5];
    const float* bv = (const float*)d_in[6];
    const float* Wo = (const float*)d_in[7];
    const float* bo = (const float*)d_in[8];
    float* out = (float*)d_out;

    u16* Qb  = (u16*)d_ws;                         // 8192*256
    u16* Kx  = Qb + (size_t)NROWS * 256;           // 2*LXK*256
    u16* Vt  = Kx + (size_t)2 * LXK * 256;         // 2*256*LXV
    u16* WoT = Vt + (size_t)2 * 256 * LXV;         // 256*256

    qkv_mfma<<<dim3(12, 32), 256, 0, stream>>>(H, Wq, Wk, Wv, Wo, bq, bk, bv, Qb, Kx, Vt, WoT);
    attn_out<<<512, 256, 0, stream>>>(Qb, Kx, Vt, WoT, bo, H, out);
}

// Round 11
// 47.820 us; speedup vs baseline: 2.3322x; 1.0715x over previous
//
#include <hip/hip_runtime.h>
#include <hip/hip_bf16.h>

#define D 256
#define NROWS 8192
#define LXK 4160         // Kx rows per batch: 64 prefix + 4096
#define LXV 4176         // Vt col stride per batch: 64 prefix + 4096 + 16 tail pad
#define VPAD 64

#define QBLK 16          // attn rows per block
#define KKEYS 80         // staged keys per block
#define SSTR 84          // Sb row stride (f32)
#define PSTR 104         // Pb row stride (u16), cols 80..95 zeroed
#define MSTR 264         // Ml row stride (u16)
#define BSTR 264         // Bs row stride (u16)

typedef unsigned int u32;
typedef unsigned short u16;

typedef short bf16x8 __attribute__((ext_vector_type(8)));
typedef float f32x4 __attribute__((ext_vector_type(4)));

__device__ __forceinline__ u16 f2bf(float f) {
    u32 x = __float_as_uint(f);
    x += 0x7fffu + ((x >> 16) & 1u);
    return (u16)(x >> 16);
}
__device__ __forceinline__ u32 pk2(float a, float b) {
    return (u32)f2bf(a) | ((u32)f2bf(b) << 16);
}

// ---------------- Kernel 1: QKV projection (W staged once; Q/Wo in fragment layout) ----------------
// grid (12, 32). Q -> Qf fragment layout: Qf[(rowtile*8+ks)*512 + (rl*4+lhi)*8 + e].
// Wo -> WoTf fragment layout (16 designated blocks): WoTf[(colt*8+ks)*512 + (cl*4+lhi)*8 + e].
__global__ __launch_bounds__(256) void qkv_mfma(
    const float* __restrict__ H,
    const float* __restrict__ Wq, const float* __restrict__ Wk,
    const float* __restrict__ Wv, const float* __restrict__ Wo,
    const float* __restrict__ bq, const float* __restrict__ bkb,
    const float* __restrict__ bvb,
    u16* __restrict__ Qf, u16* __restrict__ Kx, u16* __restrict__ Vt,
    u16* __restrict__ WoTf)
{
    __shared__ u16 As[64 * 256];        // 32768 B
    __shared__ u16 Bs[64 * BSTR];       // 33792 B
    __shared__ u16 Eb[64 * 72];         // 9216 B

    const int tid = threadIdx.x;
    const int bx = blockIdx.x;          // 0..11
    const int by = blockIdx.y;          // 0..31
    const int mat = bx >> 2;            // 0=Q 1=K 2=V
    const int n0 = (bx & 3) * 64;
    const int row0 = by * 256;
    const int batch = by >> 4;
    const int lrow0 = row0 & 4095;
    const float* __restrict__ W = (mat == 0) ? Wq : (mat == 1) ? Wk : Wv;
    const float* __restrict__ bias = (mat == 0) ? bq : (mat == 1) ? bkb : bvb;

    const int lane = tid & 63, w = tid >> 6;
    const int l15 = lane & 15, lhi = lane >> 4;
    const int rt2 = (w & 1) * 2, ct2 = (w >> 1) * 2;

    // ---- stage B once ----
    {
        const int kp = tid & 31, ng = tid >> 5;
        u32* bd = (u32*)Bs;
        #pragma unroll
        for (int s = 0; s < 4; ++s) {
            const float* wr = W + (size_t)(s * 64 + 2 * kp) * 256 + n0 + ng * 8;
            float4 a0 = *(const float4*)(wr);
            float4 a1 = *(const float4*)(wr + 4);
            float4 b0 = *(const float4*)(wr + 256);
            float4 b1 = *(const float4*)(wr + 260);
            bd[(ng * 8 + 0) * 132 + s * 32 + kp] = pk2(a0.x, b0.x);
            bd[(ng * 8 + 1) * 132 + s * 32 + kp] = pk2(a0.y, b0.y);
            bd[(ng * 8 + 2) * 132 + s * 32 + kp] = pk2(a0.z, b0.z);
            bd[(ng * 8 + 3) * 132 + s * 32 + kp] = pk2(a0.w, b0.w);
            bd[(ng * 8 + 4) * 132 + s * 32 + kp] = pk2(a1.x, b1.x);
            bd[(ng * 8 + 5) * 132 + s * 32 + kp] = pk2(a1.y, b1.y);
            bd[(ng * 8 + 6) * 132 + s * 32 + kp] = pk2(a1.z, b1.z);
            bd[(ng * 8 + 7) * 132 + s * 32 + kp] = pk2(a1.w, b1.w);
        }
    }
    // ---- stage A tile 0 ----
    {
        const int r = tid >> 2, cb = (tid & 3) * 64;
        const float* hp = H + (size_t)(row0 + r) * 256 + cb;
        const int swz = (r & 7) << 3;
        #pragma unroll
        for (int i = 0; i < 16; ++i) {
            float4 h4 = *(const float4*)(hp + i * 4);
            uint2 pv; pv.x = pk2(h4.x, h4.y); pv.y = pk2(h4.z, h4.w);
            *(uint2*)(As + ((r * 256 + cb + i * 4) ^ swz)) = pv;
        }
    }
    __syncthreads();

    for (int t = 0; t < 4; ++t) {
        f32x4 acc[2][2];
        #pragma unroll
        for (int rr = 0; rr < 2; ++rr)
            #pragma unroll
            for (int cc = 0; cc < 2; ++cc)
                acc[rr][cc] = (f32x4){0.f, 0.f, 0.f, 0.f};
        #pragma unroll
        for (int rr = 0; rr < 2; ++rr) {
            const int rowa = (rt2 + rr) * 16 + l15;
            const int swa = (rowa & 7) << 3;
            bf16x8 af[8];
            #pragma unroll
            for (int ks = 0; ks < 8; ++ks)
                af[ks] = *(const bf16x8*)(As + ((rowa * 256 + ks * 32 + lhi * 8) ^ swa));
            #pragma unroll
            for (int ks = 0; ks < 8; ++ks)
                #pragma unroll
                for (int cc = 0; cc < 2; ++cc) {
                    bf16x8 bf = *(const bf16x8*)&Bs[((ct2 + cc) * 16 + l15) * BSTR + ks * 32 + lhi * 8];
                    acc[rr][cc] = __builtin_amdgcn_mfma_f32_16x16x32_bf16(af[ks], bf, acc[rr][cc], 0, 0, 0);
                }
        }
        __syncthreads();

        // ---- epilogue writes (Eb) + next A stage ----
        if (mat == 2) {
            #pragma unroll
            for (int cc = 0; cc < 2; ++cc) {
                const int dl = (ct2 + cc) * 16 + l15;
                const float bi = bvb[n0 + dl];
                #pragma unroll
                for (int rr = 0; rr < 2; ++rr)
                    #pragma unroll
                    for (int reg = 0; reg < 4; ++reg)
                        Eb[dl * 72 + (rt2 + rr) * 16 + lhi * 4 + reg] = f2bf(acc[rr][cc][reg] + bi);
            }
        } else {
            #pragma unroll
            for (int cc = 0; cc < 2; ++cc) {
                const int cl = (ct2 + cc) * 16 + l15;
                const float bi = bias[n0 + cl];
                #pragma unroll
                for (int rr = 0; rr < 2; ++rr)
                    #pragma unroll
                    for (int reg = 0; reg < 4; ++reg)
                        Eb[((rt2 + rr) * 16 + lhi * 4 + reg) * 72 + cl] = f2bf(acc[rr][cc][reg] + bi);
            }
        }
        if (t < 3) {
            const int r = tid >> 2, cb = (tid & 3) * 64;
            const float* hp = H + (size_t)(row0 + (t + 1) * 64 + r) * 256 + cb;
            const int swz = (r & 7) << 3;
            #pragma unroll
            for (int i = 0; i < 16; ++i) {
                float4 h4 = *(const float4*)(hp + i * 4);
                uint2 pv; pv.x = pk2(h4.x, h4.y); pv.y = pk2(h4.z, h4.w);
                *(uint2*)(As + ((r * 256 + cb + i * 4) ^ swz)) = pv;
            }
        }
        __syncthreads();

        // ---- coalesced stores from Eb ----
        if (mat == 2) {
            const int d2 = tid >> 2, q = tid & 3;
            uint4 v0 = *(const uint4*)&Eb[d2 * 72 + q * 16];
            uint4 v1 = *(const uint4*)&Eb[d2 * 72 + q * 16 + 8];
            u16* dst = Vt + ((size_t)batch * 256 + n0 + d2) * LXV + VPAD + lrow0 + t * 64 + q * 16;
            *(uint4*)dst = v0;
            *(uint4*)(dst + 8) = v1;
        } else if (mat == 1) {
            const int r2 = tid >> 2, c16 = (tid & 3) * 16;
            uint4 v0 = *(const uint4*)&Eb[r2 * 72 + c16];
            uint4 v1 = *(const uint4*)&Eb[r2 * 72 + c16 + 8];
            u16* dst = Kx + ((size_t)batch * LXK + VPAD + lrow0 + t * 64 + r2) * 256 + n0 + c16;
            *(uint4*)(dst + 0) = v0;
            *(uint4*)(dst + 8) = v1;
        } else {
            // Q -> fragment layout
            const int r2 = tid >> 2, c16 = (tid & 3) * 16;
            const int grow = row0 + t * 64 + r2;
            const int rtile = grow >> 4, rl = grow & 15;
            #pragma unroll
            for (int h = 0; h < 2; ++h) {
                const int gcol = n0 + c16 + h * 8;
                const int ksq = gcol >> 5;
                const int lhq = (gcol >> 3) & 3;
                uint4 v = *(const uint4*)&Eb[r2 * 72 + c16 + h * 8];
                *(uint4*)&Qf[((size_t)rtile * 8 + ksq) * 512 + (rl * 4 + lhq) * 8] = v;
            }
        }
    }

    // ---- WoTf production: 16 blocks, one 64x64 tile each, fragment layout ----
    if (bx == 0 && by < 16) {
        float* Tf = (float*)As;     // [64][68] f32
        const int tr = by >> 2, tc = by & 3;
        __syncthreads();
        {
            const int r = tid >> 2, c0 = (tid & 3) * 16;
            const float* src = Wo + (size_t)(tr * 64 + r) * 256 + tc * 64 + c0;
            #pragma unroll
            for (int i = 0; i < 4; ++i) {
                float4 v = *(const float4*)(src + i * 4);
                Tf[r * 68 + c0 + i * 4 + 0] = v.x;
                Tf[r * 68 + c0 + i * 4 + 1] = v.y;
                Tf[r * 68 + c0 + i * 4 + 2] = v.z;
                Tf[r * 68 + c0 + i * 4 + 3] = v.w;
            }
        }
        __syncthreads();
        {
            const int n = tid >> 2, k0 = (tid & 3) * 16;
            const int gcol = tc * 64 + n;
            const int colt = gcol >> 4, cl = gcol & 15;
            const int gk = tr * 64 + k0;
            const int ksw = gk >> 5;
            const int lhw = (gk >> 3) & 3;     // even (0 or 2); chunks lhw, lhw+1
            u32 pw[8];
            #pragma unroll
            for (int i = 0; i < 8; ++i)
                pw[i] = pk2(Tf[(k0 + 2 * i) * 68 + n], Tf[(k0 + 2 * i + 1) * 68 + n]);
            u16* base = WoTf + ((size_t)colt * 8 + ksw) * 512 + (cl * 4 + lhw) * 8;
            *(uint4*)base = *(uint4*)&pw[0];
            *(uint4*)(base + 8) = *(uint4*)&pw[4];
        }
    }
    // ---- virtual prefixes ----
    if (bx == 4 && (by & 15) == 0) {          // Kx prefix rows = bk
        const int batch2 = by >> 4;
        const int rowp = tid >> 2, c64 = (tid & 3) * 64;
        u16* dst = Kx + ((size_t)batch2 * LXK + rowp) * 256 + c64;
        #pragma unroll
        for (int j = 0; j < 8; ++j) {
            float4 a = *(const float4*)&bkb[c64 + j * 8];
            float4 b = *(const float4*)&bkb[c64 + j * 8 + 4];
            uint4 o;
            o.x = pk2(a.x, a.y); o.y = pk2(a.z, a.w);
            o.z = pk2(b.x, b.y); o.w = pk2(b.z, b.w);
            *(uint4*)(dst + j * 8) = o;
        }
    }
    if (bx == 8 && (by & 15) == 0) {          // Vt prefix cols = bv
        const int batch2 = by >> 4;
        const u16 val = f2bf(bvb[tid]);
        const u32 vv = (u32)val | ((u32)val << 16);
        uint4 o; o.x = vv; o.y = vv; o.z = vv; o.w = vv;
        u16* dst = Vt + ((size_t)batch2 * 256 + tid) * LXV;
        #pragma unroll
        for (int j = 0; j < 8; ++j) *(uint4*)(dst + j * 8) = o;
    }
}

// ---------------- Kernel 2: fused attention + out-projection + residual ----------------
// 16 rows/block, grid 512, 49.7 KB LDS. Q and Wo fragments from coalesced
// fragment-layout buffers; K staged in LDS (swizzled); V^T from global.
__global__ __launch_bounds__(256) void attn_out(
    const u16* __restrict__ Qf, const u16* __restrict__ Kx,
    const u16* __restrict__ Vt, const u16* __restrict__ WoTf,
    const float* __restrict__ bo, const float* __restrict__ H,
    float* __restrict__ out)
{
    __shared__ __align__(16) char smem[49664];
    u16*  Ks = (u16*)smem;                 // [80][256] swizzled (dead after QK^T)
    u16*  Ml = (u16*)smem;                 // [16][MSTR] overlays Ks
    float* Sb = (float*)(smem + 40960);    // [16][SSTR]
    u16*  Pb = (u16*)(smem + 46336);       // [16][PSTR]

    const int tid = threadIdx.x;
    const int lane = tid & 63, w = tid >> 6;   // w 0..3
    const int l15 = lane & 15, lhi = lane >> 4;
    const int r0 = blockIdx.x * QBLK;
    const int batch = r0 >> 12;
    const int lb0 = r0 & 4095;
    const size_t kbase = (size_t)batch * LXK + lb0;

    // ---- stage K (80 rows, swizzled) ----
    uint4 kreg[10];
    #pragma unroll
    for (int i = 0; i < 10; ++i) {
        const int u = i * 256 + tid;
        const int row = u >> 5, seg = u & 31;
        kreg[i] = *(const uint4*)&Kx[(kbase + row) * 256 + seg * 8];
    }
    #pragma unroll
    for (int i = 0; i < 10; ++i) {
        const int u = i * 256 + tid;
        const int row = u >> 5, seg = u & 31;
        *(uint4*)&Ks[row * 256 + (seg ^ (row & 7)) * 8] = kreg[i];
    }
    __syncthreads();

    // ---- QK^T (Q fragments coalesced from Qf) ----
    const float scale = 0.0625f;
    const u16* qp = Qf + (size_t)(r0 >> 4) * 4096 + (l15 * 4 + lhi) * 8;
    bf16x8 qf[8];
    #pragma unroll
    for (int ks = 0; ks < 8; ++ks) qf[ks] = *(const bf16x8*)(qp + ks * 512);
    for (int T = w; T < 5; T += 4) {
        const int key = T * 16 + l15;
        f32x4 acc = (f32x4){0.f, 0.f, 0.f, 0.f};
        #pragma unroll
        for (int ks = 0; ks < 8; ++ks) {
            bf16x8 kf = *(const bf16x8*)&Ks[key * 256 + ((ks * 4 + lhi) ^ (key & 7)) * 8];
            acc = __builtin_amdgcn_mfma_f32_16x16x32_bf16(qf[ks], kf, acc, 0, 0, 0);
        }
        #pragma unroll
        for (int reg = 0; reg < 4; ++reg)
            Sb[(lhi * 4 + reg) * SSTR + T * 16 + l15] = acc[reg] * scale;
    }
    __syncthreads();

    // ---- nested softmax ----
    {
        const int ri = w * 4 + lhi;
        const int jb = l15;
        float s5[5];
        float m = -1e30f;
        #pragma unroll
        for (int c = 0; c < 5; ++c) {
            const int j = jb + 16 * c;
            const float x = Sb[ri * SSTR + j];
            const bool v = (j >= ri + 1) && (j <= ri + 64);
            s5[c] = v ? x : -1e30f;
            m = fmaxf(m, s5[c]);
        }
        #pragma unroll
        for (int o = 1; o < 16; o <<= 1) m = fmaxf(m, __shfl_xor(m, o));
        float e5[5], z64 = 0.f, z16 = 0.f, z4 = 0.f;
        #pragma unroll
        for (int c = 0; c < 5; ++c) {
            const int j = jb + 16 * c;
            const float e = __expf(s5[c] - m);
            e5[c] = e;
            z64 += e;
            if (j >= ri + 49) z16 += e;
            if (j >= ri + 61) z4 += e;
        }
        #pragma unroll
        for (int o = 1; o < 16; o <<= 1) {
            z64 += __shfl_xor(z64, o);
            z16 += __shfl_xor(z16, o);
            z4  += __shfl_xor(z4, o);
        }
        const float i64 = 1.f / z64, i16 = 1.f / z16, i4 = 1.f / z4;
        #pragma unroll
        for (int c = 0; c < 5; ++c) {
            const int j = jb + 16 * c;
            float wt = e5[c] * (i64 + (j >= ri + 49 ? i16 : 0.f) + (j >= ri + 61 ? i4 : 0.f)) * (1.f / 3.f);
            Pb[ri * PSTR + j] = f2bf(wt);
        }
        Pb[ri * PSTR + 80 + jb] = 0;
    }
    __syncthreads();

    // ---- PV: M[16][256] -> Ml (LDS); V fragments from global ----
    bf16x8 pa[3];
    #pragma unroll
    for (int ks = 0; ks < 3; ++ks)
        pa[ks] = *(const bf16x8*)&Pb[l15 * PSTR + ks * 32 + lhi * 8];
    #pragma unroll
    for (int i = 0; i < 4; ++i) {
        const int dt = w * 4 + i;
        const u16* vrow = Vt + ((size_t)batch * 256 + dt * 16 + l15) * LXV + lb0;
        f32x4 acc = (f32x4){0.f, 0.f, 0.f, 0.f};
        #pragma unroll
        for (int ks = 0; ks < 3; ++ks) {
            bf16x8 vb = *(const bf16x8*)(vrow + ks * 32 + lhi * 8);
            acc = __builtin_amdgcn_mfma_f32_16x16x32_bf16(pa[ks], vb, acc, 0, 0, 0);
        }
        #pragma unroll
        for (int reg = 0; reg < 4; ++reg)
            Ml[(lhi * 4 + reg) * MSTR + dt * 16 + l15] = f2bf(acc[reg]);
    }
    __syncthreads();

    // ---- out-GEMM: Wo fragments coalesced from WoTf ----
    bf16x8 afm[8];
    #pragma unroll
    for (int ks = 0; ks < 8; ++ks)
        afm[ks] = *(const bf16x8*)&Ml[l15 * MSTR + ks * 32 + lhi * 8];

    #pragma unroll
    for (int ct = 0; ct < 4; ++ct) {
        const int colt = w * 4 + ct;
        const u16* wrow = WoTf + (size_t)colt * 4096 + (l15 * 4 + lhi) * 8;
        f32x4 oac = (f32x4){0.f, 0.f, 0.f, 0.f};
        #pragma unroll
        for (int ks = 0; ks < 8; ++ks) {
            bf16x8 bf = *(const bf16x8*)(wrow + ks * 512);
            oac = __builtin_amdgcn_mfma_f32_16x16x32_bf16(afm[ks], bf, oac, 0, 0, 0);
        }
        const int col = w * 64 + ct * 16 + l15;
        const float bi = bo[col];
        #pragma unroll
        for (int reg = 0; reg < 4; ++reg) {
            const int r = r0 + lhi * 4 + reg;
            const size_t off = (size_t)r * 256 + col;
            out[off] = H[off] + oac[reg] + bi;
        }
    }
}

extern "C" void kernel_launch(void* const* d_in, const int* in_sizes, int n_in,
                              void* d_out, int out_size, void* d_ws, size_t ws_size,
                              hipStream_t stream) {
    const float* H  = (const float*)d_in[0];
    const float* Wq = (const float*)d_in[1];
    const float* bq = (const float*)d_in[2];
    const float* Wk = (const float*)d_in[3];
    const float* bk = (const float*)d_in[4];
    const float* Wv = (const float*)d_in[5];
    const float* bv = (const float*)d_in[6];
    const float* Wo = (const float*)d_in[7];
    const float* bo = (const float*)d_in[8];
    float* out = (float*)d_out;

    u16* Qf   = (u16*)d_ws;                        // 8192*256 (fragment layout)
    u16* Kx   = Qf + (size_t)NROWS * 256;          // 2*LXK*256
    u16* Vt   = Kx + (size_t)2 * LXK * 256;        // 2*256*LXV
    u16* WoTf = Vt + (size_t)2 * 256 * LXV;        // 256*256 (fragment layout)

    qkv_mfma<<<dim3(12, 32), 256, 0, stream>>>(H, Wq, Wk, Wv, Wo, bq, bk, bv, Qf, Kx, Vt, WoTf);
    attn_out<<<512, 256, 0, stream>>>(Qf, Kx, Vt, WoTf, bo, H, out);
}